// Round 2
// baseline (41.372 us; speedup 1.0000x reference)
//
#include <hip/hip_runtime.h>

#define L 8192
#define ATT 1024
#define NPREV 8
#define ROWS 32          // rows per score block
#define NBLK 256         // L / ROWS

__device__ inline float fast_tanh(float x) {
    // tanh(x) = 1 - 2/(exp(2x)+1); saturates correctly
    float e = __expf(2.0f * x);
    return 1.0f - 2.0f / (e + 1.0f);
}

// K1: dec_tiled[a] = dot(dec_z, mlp_dec_w[a,:]) + b[a]; wave-per-output
__global__ __launch_bounds__(256) void k_matvec(
    const float* __restrict__ dec_z, const float* __restrict__ mlp_dec_w,
    const float* __restrict__ mlp_dec_b, float* __restrict__ dec_tiled)
{
    int wave = threadIdx.x >> 6, lane = threadIdx.x & 63;
    int a = blockIdx.x * 4 + wave;
    const float4* wrow = (const float4*)(mlp_dec_w + (size_t)a * ATT);
    const float4* dz   = (const float4*)dec_z;
    float s = 0.f;
    #pragma unroll
    for (int k = 0; k < 4; ++k) {
        int i = lane + 64 * k;
        float4 wv = wrow[i];
        float4 zv = dz[i];
        s += wv.x * zv.x + wv.y * zv.y + wv.z * zv.z + wv.w * zv.w;
    }
    #pragma unroll
    for (int off = 32; off; off >>= 1) s += __shfl_down(s, off, 64);
    if (lane == 0) dec_tiled[a] = s + mlp_dec_b[a];
}

// K2 fused: coverage + att copy -> scores (unnormalized exp) -> context partial
__global__ __launch_bounds__(256) void k_score_ctx(
    const float* __restrict__ att_prev, const float* __restrict__ pre_enc,
    const float* __restrict__ enc_h,
    const float* __restrict__ wvec_w, const float* __restrict__ wvec_b,
    const float* __restrict__ dec_tiled,
    const float* __restrict__ gvec_w, const float* __restrict__ gvec_b,
    const float* __restrict__ mask,
    float* __restrict__ out_att,  // [NPREV][L] copies
    float* __restrict__ u,        // [L] unnormalized softmax numerators
    float* __restrict__ usum,     // [NBLK] per-block sums of u
    float* __restrict__ partial)  // [NBLK][ATT] context partials
{
    __shared__ float u_s[ROWS];
    __shared__ float cov_s[ROWS];
    int t = threadIdx.x;
    int b = blockIdx.x;
    int base = b * ROWS;

    // phase 0: coverage + copy old attention rows (coalesced per-p)
    if (t < ROWS) {
        float s = 0.f;
        #pragma unroll
        for (int p = 0; p < NPREV; ++p) {
            float v = att_prev[p * L + base + t];
            out_att[p * L + base + t] = v;
            s += v;
        }
        cov_s[t] = s;
    }
    __syncthreads();

    // hoist broadcast vectors into registers (reused across all 8 rows)
    int wave = t >> 6, lane = t & 63;
    const float4* ww = (const float4*)wvec_w;
    const float4* wb = (const float4*)wvec_b;
    const float4* dt = (const float4*)dec_tiled;
    const float4* gw = (const float4*)gvec_w;
    float4 W4[4], BD4[4], G4[4];
    #pragma unroll
    for (int k = 0; k < 4; ++k) {
        int i = lane + 64 * k;
        W4[k] = ww[i];
        float4 b4 = wb[i], d4 = dt[i];
        BD4[k] = make_float4(b4.x + d4.x, b4.y + d4.y, b4.z + d4.z, b4.w + d4.w);
        G4[k] = gw[i];
    }
    float gb = gvec_b[0];

    // phase 1: each wave scores 8 rows
    #pragma unroll
    for (int r8 = 0; r8 < 8; ++r8) {
        int r = wave * 8 + r8;
        int l = base + r;
        float cv = cov_s[r];
        const float4* row = (const float4*)(pre_enc + (size_t)l * ATT);
        float s = 0.f;
        #pragma unroll
        for (int k = 0; k < 4; ++k) {
            float4 pe = row[lane + 64 * k];
            s += fast_tanh(cv * W4[k].x + BD4[k].x + pe.x) * G4[k].x;
            s += fast_tanh(cv * W4[k].y + BD4[k].y + pe.y) * G4[k].y;
            s += fast_tanh(cv * W4[k].z + BD4[k].z + pe.z) * G4[k].z;
            s += fast_tanh(cv * W4[k].w + BD4[k].w + pe.w) * G4[k].w;
        }
        #pragma unroll
        for (int off = 32; off; off >>= 1) s += __shfl_down(s, off, 64);
        if (lane == 0) {
            // bounded |2(s+gb+mask)| <= 2*sum|gw| ~ 33  ->  exp safe in f32
            float uv = __expf(2.0f * (s + gb + mask[l]));
            u_s[r] = uv;
            u[l] = uv;
        }
    }
    __syncthreads();

    if (t == 0) {
        float s = 0.f;
        #pragma unroll
        for (int r = 0; r < ROWS; ++r) s += u_s[r];
        usum[b] = s;
    }

    // phase 2: context partial over this block's rows; thread t owns cols 4t..4t+3
    float4 acc = {0.f, 0.f, 0.f, 0.f};
    const float4* enc = (const float4*)enc_h;
    #pragma unroll 4
    for (int r = 0; r < ROWS; ++r) {
        float uv = u_s[r];
        float4 v = enc[(size_t)(base + r) * (ATT / 4) + t];
        acc.x += uv * v.x; acc.y += uv * v.y;
        acc.z += uv * v.z; acc.w += uv * v.w;
    }
    ((float4*)partial)[b * (ATT / 4) + t] = acc;
}

// K3: blocks 0..3 -> c columns; blocks 4..35 -> normalized w
__global__ __launch_bounds__(256) void k_finalize(
    const float* __restrict__ usum, const float* __restrict__ u,
    const float* __restrict__ partial,
    float* __restrict__ out_c, float* __restrict__ out_w)
{
    __shared__ float red[4];
    __shared__ float s_inv;
    int t = threadIdx.x;
    float v = usum[t];
    #pragma unroll
    for (int off = 32; off; off >>= 1) v += __shfl_down(v, off, 64);
    if ((t & 63) == 0) red[t >> 6] = v;
    __syncthreads();
    if (t == 0) s_inv = 1.0f / (red[0] + red[1] + red[2] + red[3]);
    __syncthreads();
    float inv = s_inv;
    int b = blockIdx.x;
    if (b < 4) {
        int j = b * 256 + t;
        float s = 0.f;
        #pragma unroll 8
        for (int k = 0; k < NBLK; ++k) s += partial[k * ATT + j];
        out_c[j] = s * inv;
    } else {
        int l = (b - 4) * 256 + t;
        out_w[l] = u[l] * inv;
    }
}

extern "C" void kernel_launch(void* const* d_in, const int* in_sizes, int n_in,
                              void* d_out, int out_size, void* d_ws, size_t ws_size,
                              hipStream_t stream) {
    const float* dec_z     = (const float*)d_in[0];
    const float* att_prev  = (const float*)d_in[1];
    const float* pre_enc   = (const float*)d_in[2];
    const float* enc_h     = (const float*)d_in[3];
    const float* mask      = (const float*)d_in[4];
    const float* wvec_w    = (const float*)d_in[5];
    const float* wvec_b    = (const float*)d_in[6];
    const float* mlp_dec_w = (const float*)d_in[7];
    const float* mlp_dec_b = (const float*)d_in[8];
    const float* gvec_w    = (const float*)d_in[9];
    const float* gvec_b    = (const float*)d_in[10];

    float* out     = (float*)d_out;
    float* out_c   = out;          // [1024]
    float* out_att = out + 1024;   // [9*8192]

    float* ws        = (float*)d_ws;
    float* dec_tiled = ws;                      // 1024
    float* u         = ws + 1024;               // 8192
    float* usum      = ws + 1024 + 8192;        // 256
    float* partial   = ws + 1024 + 8192 + 256;  // 256*1024

    k_matvec<<<256, 256, 0, stream>>>(dec_z, mlp_dec_w, mlp_dec_b, dec_tiled);
    k_score_ctx<<<NBLK, 256, 0, stream>>>(att_prev, pre_enc, enc_h,
                                          wvec_w, wvec_b, dec_tiled,
                                          gvec_w, gvec_b, mask,
                                          out_att, u, usum, partial);
    k_finalize<<<36, 256, 0, stream>>>(usum, u, partial, out_c, out_att + 8 * L);
}

// Round 3
// 25.185 us; speedup vs baseline: 1.6427x; 1.6427x over previous
//
#include <hip/hip_runtime.h>

#define L 8192
#define ATT 1024
#define NPREV 8

__device__ inline float fast_tanh(float x) {
    // tanh(x) = 1 - 2/(exp(2x)+1); saturates correctly
    float e = __expf(2.0f * x);
    return 1.0f - 2.0f / (e + 1.0f);
}

// K1: blocks 0..255: bd[a] = dot(dec_z, mlp_dec_w[a,:]) + mlp_dec_b[a] + wvec_b[a]
//     blocks 256..287: cov[l] = sum_p att_prev[p][l]; copy old att rows to out
__global__ __launch_bounds__(256) void k_prep(
    const float* __restrict__ dec_z, const float* __restrict__ mlp_dec_w,
    const float* __restrict__ mlp_dec_b, const float* __restrict__ wvec_b,
    const float* __restrict__ att_prev,
    float* __restrict__ bd, float* __restrict__ cov, float* __restrict__ out_att)
{
    int b = blockIdx.x, t = threadIdx.x;
    if (b < 256) {
        int wave = t >> 6, lane = t & 63;
        int a = b * 4 + wave;
        const float4* wrow = (const float4*)(mlp_dec_w + (size_t)a * ATT);
        const float4* dz   = (const float4*)dec_z;
        float s = 0.f;
        #pragma unroll
        for (int k = 0; k < 4; ++k) {
            float4 wv = wrow[lane + 64 * k];
            float4 zv = dz[lane + 64 * k];
            s += wv.x * zv.x + wv.y * zv.y + wv.z * zv.z + wv.w * zv.w;
        }
        #pragma unroll
        for (int off = 32; off; off >>= 1) s += __shfl_down(s, off, 64);
        if (lane == 0) bd[a] = s + mlp_dec_b[a] + wvec_b[a];
    } else {
        int l = (b - 256) * 256 + t;
        float s = 0.f;
        #pragma unroll
        for (int p = 0; p < NPREV; ++p) {
            float v = att_prev[p * L + l];
            out_att[p * L + l] = v;
            s += v;
        }
        cov[l] = s;
    }
}

// K2: 256 blocks x 1024 threads (16 waves = 4/SIMD). Block handles 32 rows:
// score (2 rows/wave, unnormalized exp -> out row 8) then ctx partial.
__global__ __launch_bounds__(1024, 4) void k_score_ctx(
    const float* __restrict__ pre_enc, const float* __restrict__ enc_h,
    const float* __restrict__ cov, const float* __restrict__ wvec_w,
    const float* __restrict__ bd, const float* __restrict__ gvec_w,
    const float* __restrict__ gvec_b, const float* __restrict__ mask,
    float* __restrict__ u_out,    // out_att row 8 (unnormalized)
    float* __restrict__ usum,     // [256] per-block sums
    float* __restrict__ partial)  // [256][ATT]
{
    __shared__ float u_s[32];
    __shared__ float4 cred[3 * 256];
    int t = threadIdx.x, b = blockIdx.x;
    int base = b * 32;
    int wave = t >> 6, lane = t & 63;

    const float4* ww  = (const float4*)wvec_w;
    const float4* bdv = (const float4*)bd;
    const float4* gw  = (const float4*)gvec_w;
    float4 W4[4], BD4[4], G4[4];
    #pragma unroll
    for (int k = 0; k < 4; ++k) {
        W4[k]  = ww[lane + 64 * k];
        BD4[k] = bdv[lane + 64 * k];
        G4[k]  = gw[lane + 64 * k];
    }
    float gb = gvec_b[0];

    #pragma unroll
    for (int rr = 0; rr < 2; ++rr) {
        int r = wave * 2 + rr;
        int l = base + r;
        float cv = cov[l];
        const float4* row = (const float4*)(pre_enc + (size_t)l * ATT);
        float4 pe[4];
        #pragma unroll
        for (int k = 0; k < 4; ++k) pe[k] = row[lane + 64 * k];
        float s = 0.f;
        #pragma unroll
        for (int k = 0; k < 4; ++k) {
            s += fast_tanh(fmaf(cv, W4[k].x, BD4[k].x) + pe[k].x) * G4[k].x;
            s += fast_tanh(fmaf(cv, W4[k].y, BD4[k].y) + pe[k].y) * G4[k].y;
            s += fast_tanh(fmaf(cv, W4[k].z, BD4[k].z) + pe[k].z) * G4[k].z;
            s += fast_tanh(fmaf(cv, W4[k].w, BD4[k].w) + pe[k].w) * G4[k].w;
        }
        #pragma unroll
        for (int off = 32; off; off >>= 1) s += __shfl_down(s, off, 64);
        if (lane == 0) {
            // |2(s+gb+mask)| <= 2*sum|gw| ~ 33 -> exp safe in f32, no max pass
            float uv = __expf(2.0f * (s + gb + mask[l]));
            u_s[r] = uv;
            u_out[l] = uv;
        }
    }
    __syncthreads();

    if (t == 0) {
        float s = 0.f;
        #pragma unroll
        for (int r = 0; r < 32; ++r) s += u_s[r];
        usum[b] = s;
    }

    // ctx: quarter rq handles rows rq*8 .. rq*8+7; thread owns one float4-col
    int jj = t & 255, rq = t >> 8;
    const float4* enc = (const float4*)enc_h;
    float4 acc = {0.f, 0.f, 0.f, 0.f};
    #pragma unroll
    for (int r = 0; r < 8; ++r) {
        float uv = u_s[rq * 8 + r];
        float4 v = enc[(size_t)(base + rq * 8 + r) * 256 + jj];
        acc.x += uv * v.x; acc.y += uv * v.y;
        acc.z += uv * v.z; acc.w += uv * v.w;
    }
    if (rq > 0) cred[(rq - 1) * 256 + jj] = acc;
    __syncthreads();
    if (rq == 0) {
        float4 a1 = cred[jj], a2 = cred[256 + jj], a3 = cred[512 + jj];
        acc.x += a1.x + a2.x + a3.x;
        acc.y += a1.y + a2.y + a3.y;
        acc.z += a1.z + a2.z + a3.z;
        acc.w += a1.w + a2.w + a3.w;
        ((float4*)partial)[b * 256 + jj] = acc;
    }
}

// K3: blocks 0..63 -> c (4 float4-cols each, reduce 256 partials); 64..95 -> scale w
__global__ __launch_bounds__(256) void k_finalize(
    const float* __restrict__ usum, const float* __restrict__ partial,
    float* __restrict__ out_c, float* __restrict__ w_inplace)
{
    __shared__ float red[4];
    __shared__ float s_inv_sh;
    __shared__ float4 wred[4][4];
    int t = threadIdx.x, b = blockIdx.x;
    int wave = t >> 6, lane = t & 63;

    float v = usum[t];
    #pragma unroll
    for (int off = 32; off; off >>= 1) v += __shfl_down(v, off, 64);
    if (lane == 0) red[wave] = v;
    __syncthreads();
    if (t == 0) s_inv_sh = 1.0f / (red[0] + red[1] + red[2] + red[3]);
    __syncthreads();
    float inv = s_inv_sh;

    if (b < 64) {
        int c = t & 3, r = t >> 2;  // r in [0,64)
        const float4* p4 = (const float4*)partial;
        float4 a = {0.f, 0.f, 0.f, 0.f};
        #pragma unroll
        for (int i = 0; i < 4; ++i) {
            float4 vv = p4[(r + 64 * i) * 256 + b * 4 + c];
            a.x += vv.x; a.y += vv.y; a.z += vv.z; a.w += vv.w;
        }
        #pragma unroll
        for (int off = 4; off <= 32; off <<= 1) {
            a.x += __shfl_xor(a.x, off, 64);
            a.y += __shfl_xor(a.y, off, 64);
            a.z += __shfl_xor(a.z, off, 64);
            a.w += __shfl_xor(a.w, off, 64);
        }
        if (lane < 4) wred[wave][lane] = a;  // lane==c here (r&15==0)
        __syncthreads();
        if (t < 4) {
            float4 s0 = wred[0][t], s1 = wred[1][t], s2 = wred[2][t], s3 = wred[3][t];
            float4 o;
            o.x = (s0.x + s1.x + s2.x + s3.x) * inv;
            o.y = (s0.y + s1.y + s2.y + s3.y) * inv;
            o.z = (s0.z + s1.z + s2.z + s3.z) * inv;
            o.w = (s0.w + s1.w + s2.w + s3.w) * inv;
            ((float4*)out_c)[b * 4 + t] = o;
        }
    } else {
        int l = (b - 64) * 256 + t;
        w_inplace[l] *= inv;
    }
}

extern "C" void kernel_launch(void* const* d_in, const int* in_sizes, int n_in,
                              void* d_out, int out_size, void* d_ws, size_t ws_size,
                              hipStream_t stream) {
    const float* dec_z     = (const float*)d_in[0];
    const float* att_prev  = (const float*)d_in[1];
    const float* pre_enc   = (const float*)d_in[2];
    const float* enc_h     = (const float*)d_in[3];
    const float* mask      = (const float*)d_in[4];
    const float* wvec_w    = (const float*)d_in[5];
    const float* wvec_b    = (const float*)d_in[6];
    const float* mlp_dec_w = (const float*)d_in[7];
    const float* mlp_dec_b = (const float*)d_in[8];
    const float* gvec_w    = (const float*)d_in[9];
    const float* gvec_b    = (const float*)d_in[10];

    float* out     = (float*)d_out;
    float* out_c   = out;          // [1024]
    float* out_att = out + 1024;   // [9*8192]
    float* out_w   = out_att + 8 * L;

    float* ws      = (float*)d_ws;
    float* bd      = ws;                       // 1024
    float* cov     = ws + 1024;                // 8192
    float* usum    = ws + 1024 + 8192;         // 256
    float* partial = ws + 1024 + 8192 + 256;   // 256*1024

    k_prep<<<288, 256, 0, stream>>>(dec_z, mlp_dec_w, mlp_dec_b, wvec_b,
                                    att_prev, bd, cov, out_att);
    k_score_ctx<<<256, 1024, 0, stream>>>(pre_enc, enc_h, cov, wvec_w, bd,
                                          gvec_w, gvec_b, mask,
                                          out_w, usum, partial);
    k_finalize<<<96, 256, 0, stream>>>(usum, partial, out_c, out_w);
}